// Round 10
// baseline (189.140 us; speedup 1.0000x reference)
//
#include <hip/hip_runtime.h>
#include <hip/hip_cooperative_groups.h>

namespace cg = cooperative_groups;

#define WSTRIDE 8704   // padded row stride for wab (shifted layout, max idx 8452)

__device__ __forceinline__ float lrelu(float x) { return x > 0.0f ? x : 0.01f * x; }

// gemm 512x512 phase: Ot[j][b] = lrelu(sum_k At[k][b]*W[k][j] + bias[j])
// grid is exactly 256 = 8 jt x 32 bt; 512 thr = 8 k-split waves; tile 64j x 4b.
__device__ __forceinline__ void gemm512_phase(const float* __restrict__ At,
                                              const float* __restrict__ W,
                                              const float* __restrict__ bias,
                                              float* __restrict__ Ot,
                                              float* smem, int tid) {
    float (*As)[4] = (float (*)[4])smem;                    // 2048 floats
    float (*red)[64][5] = (float (*)[64][5])(smem + 2048);  // 8*64*5 = 2560
    int jt = blockIdx.x & 7;
    int bt = blockIdx.x >> 3;          // 0..31
    int lane = tid & 63;
    int wid  = __builtin_amdgcn_readfirstlane(tid >> 6);  // 0..7
    int b0 = bt * 4;
#pragma unroll
    for (int r = 0; r < 2; ++r) {
        int p = r * 512 + tid;
        int k = p >> 1, q = p & 1;
        *(float2*)&As[k][q * 2] = *(const float2*)&At[k * 128 + b0 + q * 2];
    }
    __syncthreads();
    int j = jt * 64 + lane;
    float acc[4] = {};
    int k0 = wid * 64;
#pragma unroll 8
    for (int kk = 0; kk < 64; ++kk) {
        int k = k0 + kk;
        float4 a = *(const float4*)&As[k][0];   // LDS broadcast
        float w = W[k * 512 + j];               // coalesced dword
        acc[0] = fmaf(a.x, w, acc[0]);
        acc[1] = fmaf(a.y, w, acc[1]);
        acc[2] = fmaf(a.z, w, acc[2]);
        acc[3] = fmaf(a.w, w, acc[3]);
    }
#pragma unroll
    for (int i = 0; i < 4; ++i) red[wid][lane][i] = acc[i];
    __syncthreads();
    if (tid < 256) {
        int jj = tid >> 2;
        int bb = tid & 3;
        float s = 0.f;
#pragma unroll
        for (int w = 0; w < 8; ++w) s += red[w][jj][bb];
        int jg = jt * 64 + jj;
        Ot[jg * 128 + b0 + bb] = lrelu(s + bias[jg]);
    }
    __syncthreads();   // smem dead before reuse
}

__global__ __launch_bounds__(512, 2)
void fused_kernel(const float* __restrict__ z,    const float* __restrict__ logP,
                  const float* __restrict__ hW0,  const float* __restrict__ hb0,
                  const float* __restrict__ hW1,  const float* __restrict__ hb1,
                  const float* __restrict__ hW2,  const float* __restrict__ hb2,
                  const float* __restrict__ hWo,  const float* __restrict__ hbo,
                  float* __restrict__ out,        float* __restrict__ wab,
                  float* __restrict__ h0T,        float* __restrict__ h1T,
                  float* __restrict__ h2T) {
    __shared__ __align__(16) float smem[8960];   // 35.8 KB, reused per phase
    cg::grid_group grid = cg::this_grid();
    int tid = threadIdx.x;

    // ---- Phase A0: h0T[j][b] = lrelu(z[b,:16] @ W0[:,j] + b0[j]) ----
    if (tid < 256) {
        int j = blockIdx.x * 2 + (tid >> 7);   // 0..511
        int b = tid & 127;
        float zr[16];
        *(float4*)&zr[0]  = *(const float4*)&z[b * 16 + 0];
        *(float4*)&zr[4]  = *(const float4*)&z[b * 16 + 4];
        *(float4*)&zr[8]  = *(const float4*)&z[b * 16 + 8];
        *(float4*)&zr[12] = *(const float4*)&z[b * 16 + 12];
        float acc = hb0[j];
#pragma unroll
        for (int l = 0; l < 16; ++l) acc = fmaf(zr[l], hW0[l * 512 + j], acc);
        h0T[j * 128 + b] = lrelu(acc);
    }
    grid.sync();

    // ---- Phase A1/A2: the two 512x512 hidden layers ----
    gemm512_phase(h0T, hW1, hb1, h1T, smem, tid);
    grid.sync();
    gemm512_phase(h1T, hW2, hb2, h2T, smem, tid);
    grid.sync();

    // ---- Phase B: wab[b][dest(j)] = h2 @ hWo + hbo; dest(j)=j+(j>=65?3:0) ----
    // 1072 tiles = 67 jt (128 j) x 16 bt (8 b); k-split 8; grid-stride by 256.
    {
        float (*As)[8] = (float (*)[8])smem;     // 4096 floats
        int lane = tid & 63;
        int wid = __builtin_amdgcn_readfirstlane(tid >> 6);  // 0..7
        for (int t = blockIdx.x; t < 1072; t += 256) {
            int jt = t >> 4;               // 0..66
            int bt = t & 15;               // 0..15
            int b0 = bt * 8;
            // stage At[0:512][b0:b0+8] (float4, coalesced)
#pragma unroll
            for (int r = 0; r < 2; ++r) {
                int p = r * 512 + tid;     // 0..1023
                int k = p >> 1, h = (p & 1) * 4;
                *(float4*)&As[k][h] = *(const float4*)&h2T[k * 128 + b0 + h];
            }
            __syncthreads();
            int j0r = jt * 128 + lane * 2;
            int j0 = j0r <= 8448 ? j0r : 8448;   // clamp (even -> aligned float2)
            int k0 = wid * 64;
            const float* __restrict__ Wp = hWo + (size_t)k0 * 8450 + j0;
            float acc[8][2];
#pragma unroll
            for (int i = 0; i < 8; ++i) { acc[i][0] = 0.f; acc[i][1] = 0.f; }
#pragma unroll 4
            for (int kk = 0; kk < 64; ++kk) {
                float4 aL = *(const float4*)&As[k0 + kk][0];   // LDS broadcast
                float4 aH = *(const float4*)&As[k0 + kk][4];
                float2 w = *(const float2*)(Wp + (size_t)kk * 8450);
                float av[8] = {aL.x, aL.y, aL.z, aL.w, aH.x, aH.y, aH.z, aH.w};
#pragma unroll
                for (int i = 0; i < 8; ++i) {
                    acc[i][0] = fmaf(av[i], w.x, acc[i][0]);
                    acc[i][1] = fmaf(av[i], w.y, acc[i][1]);
                }
            }
            __syncthreads();               // As dead; overlay partials
#pragma unroll
            for (int i = 0; i < 8; ++i) {
                smem[(wid * 8 + i) * 132 + lane * 2 + 0] = acc[i][0];
                smem[(wid * 8 + i) * 132 + lane * 2 + 1] = acc[i][1];
            }
            __syncthreads();
            // final reduce: thread -> (j, 2 b's)
            int j = tid & 127;
            int bs = tid >> 7;             // 0..3
            int jg = jt * 128 + j;
            if (jg < 8450) {
                float bj = hbo[jg];
                int dst = jg + (jg >= 65 ? 3 : 0);
#pragma unroll
                for (int q = 0; q < 2; ++q) {
                    int bb = bs * 2 + q;
                    float s = 0.f;
#pragma unroll
                    for (int w = 0; w < 8; ++w) s += smem[(w * 8 + bb) * 132 + j];
                    wab[(size_t)(b0 + bb) * WSTRIDE + dst] = s + bj;
                }
            }
            __syncthreads();               // before next tile's stage
        }
    }
    grid.sync();

    // ---- Phase C: decoder. wab row (shifted): w0[0:64], b0[64], pad, W1[68:4164),
    // b1[4164:4228), W2[4228:8324), b2[8324:8388), w3[8388:8452), b3[8452]. ----
    {
        float* hX = smem;                  // 64*65 = 4160
        float* hY = smem + 4160;           // 4160
        float* red = smem + 8320;          // 8*68 = 544
        int b  = blockIdx.x >> 1;
        int gh = blockIdx.x & 1;
        int lane = tid & 63;
        int jq = (tid >> 6) * 8;           // vector path (no readfirstlane)
        int g = gh * 64 + lane;
        bool act = g < 100;
        const float* __restrict__ row = wab + (size_t)b * WSTRIDE;
        float x0 = act ? logP[b * 100 + g] * (1.0f / 3.0f) : 0.0f;
        float c0 = row[64];
#pragma unroll
        for (int t = 0; t < 8; ++t)
            hX[(jq + t) * 65 + lane] = __sinf(30.0f * fmaf(x0, row[jq + t], c0));
        __syncthreads();
        // layer 1
        {
            float a[8];
#pragma unroll
            for (int t = 0; t < 8; ++t) a[t] = row[4164 + jq + t];
#pragma unroll 4
            for (int i = 0; i < 64; ++i) {
                float hi = hX[i * 65 + lane];
                const float* wr = row + 68 + i * 64 + jq;   // 16B aligned
                float4 w0 = *(const float4*)&wr[0];
                float4 w1 = *(const float4*)&wr[4];
                a[0] = fmaf(hi, w0.x, a[0]);  a[1] = fmaf(hi, w0.y, a[1]);
                a[2] = fmaf(hi, w0.z, a[2]);  a[3] = fmaf(hi, w0.w, a[3]);
                a[4] = fmaf(hi, w1.x, a[4]);  a[5] = fmaf(hi, w1.y, a[5]);
                a[6] = fmaf(hi, w1.z, a[6]);  a[7] = fmaf(hi, w1.w, a[7]);
            }
#pragma unroll
            for (int t = 0; t < 8; ++t) hY[(jq + t) * 65 + lane] = __sinf(a[t]);
        }
        __syncthreads();
        // layer 2
        {
            float a[8];
#pragma unroll
            for (int t = 0; t < 8; ++t) a[t] = row[8324 + jq + t];
#pragma unroll 4
            for (int i = 0; i < 64; ++i) {
                float hi = hY[i * 65 + lane];
                const float* wr = row + 4228 + i * 64 + jq;
                float4 w0 = *(const float4*)&wr[0];
                float4 w1 = *(const float4*)&wr[4];
                a[0] = fmaf(hi, w0.x, a[0]);  a[1] = fmaf(hi, w0.y, a[1]);
                a[2] = fmaf(hi, w0.z, a[2]);  a[3] = fmaf(hi, w0.w, a[3]);
                a[4] = fmaf(hi, w1.x, a[4]);  a[5] = fmaf(hi, w1.y, a[5]);
                a[6] = fmaf(hi, w1.z, a[6]);  a[7] = fmaf(hi, w1.w, a[7]);
            }
#pragma unroll
            for (int t = 0; t < 8; ++t) hX[(jq + t) * 65 + lane] = __sinf(a[t]);
        }
        __syncthreads();
        // layer 3
        float p = 0.f;
#pragma unroll
        for (int t = 0; t < 8; ++t)
            p = fmaf(hX[(jq + t) * 65 + lane], row[8388 + jq + t], p);
        red[(tid >> 6) * 68 + lane] = p;
        __syncthreads();
        if (tid < 64 && act) {
            float s = row[8452];
#pragma unroll
            for (int w = 0; w < 8; ++w) s += red[w * 68 + lane];
            out[b * 100 + g] = fmaf(s, 500.0f, 1500.0f);
        }
    }
}

extern "C" void kernel_launch(void* const* d_in, const int* in_sizes, int n_in,
                              void* d_out, int out_size, void* d_ws, size_t ws_size,
                              hipStream_t stream) {
    const float* z    = (const float*)d_in[0];
    const float* logP = (const float*)d_in[1];
    const float* hW0  = (const float*)d_in[2];
    const float* hb0  = (const float*)d_in[3];
    const float* hW1  = (const float*)d_in[4];
    const float* hb1  = (const float*)d_in[5];
    const float* hW2  = (const float*)d_in[6];
    const float* hb2  = (const float*)d_in[7];
    const float* hWo  = (const float*)d_in[8];
    const float* hbo  = (const float*)d_in[9];
    float* out = (float*)d_out;

    float* wab = (float*)d_ws;               // 128*8704 floats (4.46 MB)
    float* h0T = wab + 128 * WSTRIDE;        // 512*128 floats
    float* h1T = h0T + 512 * 128;
    float* h2T = h1T + 512 * 128;            // total ~5.25 MB

    void* args[] = {&z, &logP, &hW0, &hb0, &hW1, &hb1, &hW2, &hb2,
                    &hWo, &hbo, &out, &wab, &h0T, &h1T, &h2T};
    hipLaunchCooperativeKernel((void*)fused_kernel, dim3(256), dim3(512),
                               args, 0, stream);
}

// Round 11
// 83.747 us; speedup vs baseline: 2.2585x; 2.2585x over previous
//
#include <hip/hip_runtime.h>

#define WSTRIDE 8704   // padded row stride for wab (shifted layout, max idx 8452)

__device__ __forceinline__ float lrelu(float x) { return x > 0.0f ? x : 0.01f * x; }

// h0T[j][b] = lrelu(sum_l z[b][l]*W0[l][j] + b0[j]); one block per j, lane = b
__global__ __launch_bounds__(128) void h0T_kernel(const float* __restrict__ z,
                                                  const float* __restrict__ W,
                                                  const float* __restrict__ bias,
                                                  float* __restrict__ h0T) {
    int j = blockIdx.x;          // 0..511
    int b = threadIdx.x;         // 0..127
    float zr[16];
    *(float4*)&zr[0]  = *(const float4*)&z[b * 16 + 0];
    *(float4*)&zr[4]  = *(const float4*)&z[b * 16 + 4];
    *(float4*)&zr[8]  = *(const float4*)&z[b * 16 + 8];
    *(float4*)&zr[12] = *(const float4*)&z[b * 16 + 12];
    float acc = bias[j];
#pragma unroll
    for (int l = 0; l < 16; ++l) acc = fmaf(zr[l], W[l * 512 + j], acc);
    h0T[j * 128 + b] = lrelu(acc);
}

// OT[j][b] = lrelu(sum_k At[k][b]*W[k][j] + bias[j]); At is [512][128]
// Tile 64j x 4b, ks8 (512 thr). Lane = bg*16+jg: jl=4 (W float4, aligned since
// 512%4==0), bb=1 (A scalar, 4-address VMEM broadcast — NOT wave-uniform, so no
// SMEM scalarization). No LDS in k-loop. Grid 256 = 8 jt x 32 bt.
__global__ __launch_bounds__(512) void gemmT_kernel(const float* __restrict__ At,
                                                    const float* __restrict__ W,
                                                    const float* __restrict__ bias,
                                                    float* __restrict__ OT) {
    __shared__ float red[8][64][5];    // 10 KB; stride 5 (coprime 32) -> conflict-free
    int jt = blockIdx.x & 7;
    int bt = blockIdx.x >> 3;          // 0..31
    int tid = threadIdx.x;
    int lane = tid & 63;
    int wid  = __builtin_amdgcn_readfirstlane(tid >> 6);  // 0..7
    int jg = lane & 15;
    int bg = lane >> 4;                // 0..3
    int j0 = jt * 64 + jg * 4;
    int b  = bt * 4 + bg;
    int k0 = wid * 64;
    float acc[4] = {};
#pragma unroll 4
    for (int kk = 0; kk < 64; ++kk) {
        int k = k0 + kk;
        float a = At[k * 128 + b];                   // 4-addr VMEM broadcast
        float4 wv = *(const float4*)&W[k * 512 + j0];
        acc[0] = fmaf(a, wv.x, acc[0]);
        acc[1] = fmaf(a, wv.y, acc[1]);
        acc[2] = fmaf(a, wv.z, acc[2]);
        acc[3] = fmaf(a, wv.w, acc[3]);
    }
#pragma unroll
    for (int e = 0; e < 4; ++e) red[wid][lane][e] = acc[e];
    __syncthreads();
    if (tid < 256) {
        int bl = tid & 3;              // b-local (store-coalescing order)
        int jj = tid >> 2;             // 0..63
        int lane_r = bl * 16 + (jj >> 2);
        int e_r = jj & 3;
        float s = 0.f;
#pragma unroll
        for (int w = 0; w < 8; ++w) s += red[w][lane_r][e_r];
        int jglob = jt * 64 + jj;
        OT[jglob * 128 + bt * 4 + bl] = lrelu(s + bias[jglob]);
    }
}

// wab[b][dest(j)] = sum_k At[k][b]*hWo[k][j] + hbo[j]; dest(j)=j+(j>=65?3:0)
// Main: j 0..8191 = 64 jt x 128j; b: 8 bt x 16b; ks4 (256 thr). Lane = bg*16+jg:
// jl=8 (W 4x float2), bb=4 (A float4, 8-addr VMEM broadcast). acc[4][8]=32 regs.
// Grid 512 EXACT (2 blocks/CU, no tail imbalance), XCD-grouped (8 bt of one jt
// share an XCD's L2 -> W slice cached). Reduce: red[4][64][32] with XOR-swizzle
// (bank = e^lane -> conflict-free). Tail j 8192..8449: 4128 (col,b-octet) dot
// units spread evenly: 16 units/block x 16 threads each (+3% work, balanced).
__global__ __launch_bounds__(256, 2) void wabT_kernel(const float* __restrict__ At,
                                                      const float* __restrict__ W,
                                                      const float* __restrict__ bias,
                                                      float* __restrict__ wab) {
    __shared__ float red[4 * 64 * 32];   // 32 KB
    int tid = threadIdx.x;
    int lane = tid & 63;
    int wid = __builtin_amdgcn_readfirstlane(tid >> 6);  // 0..3
    int B = blockIdx.x;
    int idx = (B & 7) * 64 + (B >> 3);   // XCD-grouped: same-jt blocks on one XCD
    int jt = idx >> 3;                   // 0..63
    int bt = idx & 7;                    // 0..7
    int jg = lane & 15;
    int bg = lane >> 4;                  // 0..3
    int j0 = jt * 128 + jg * 8;
    int b0 = bt * 16 + bg * 4;
    int k0 = wid * 128;
    const float* __restrict__ Ap = At + k0 * 128 + b0;
    const float* __restrict__ Wp = W + (size_t)k0 * 8450 + j0;
    float acc[4][8];
#pragma unroll
    for (int i = 0; i < 4; ++i)
#pragma unroll
        for (int jj = 0; jj < 8; ++jj) acc[i][jj] = 0.f;
#pragma unroll 4
    for (int kk = 0; kk < 128; ++kk) {
        float4 a = *(const float4*)(Ap + kk * 128);      // 8-addr VMEM broadcast
        const float* wr = Wp + (size_t)kk * 8450;
        float2 u0 = *(const float2*)(wr + 0);
        float2 u1 = *(const float2*)(wr + 2);
        float2 u2 = *(const float2*)(wr + 4);
        float2 u3 = *(const float2*)(wr + 6);
        float av[4] = {a.x, a.y, a.z, a.w};
        float wv[8] = {u0.x, u0.y, u1.x, u1.y, u2.x, u2.y, u3.x, u3.y};
#pragma unroll
        for (int i = 0; i < 4; ++i)
#pragma unroll
            for (int jj = 0; jj < 8; ++jj)
                acc[i][jj] = fmaf(av[i], wv[jj], acc[i][jj]);
    }
    // dump: bank = e ^ lane -> conflict-free (2-way lane/lane+32 is free)
#pragma unroll
    for (int i = 0; i < 4; ++i)
#pragma unroll
        for (int jj = 0; jj < 8; ++jj) {
            int e = i * 8 + jj;
            red[wid * 2048 + lane * 32 + (e ^ (lane & 31))] = acc[i][jj];
        }
    __syncthreads();
    // final: thread t -> b-local bl=t>>4, j = (t&15)*8 + r
    {
        int bl = tid >> 4;               // 0..15
        int jgr = tid & 15;
        int lane_r = (bl >> 2) * 16 + jgr;
        int swz = lane_r & 31;
        float* drow = wab + (size_t)(bt * 16 + bl) * WSTRIDE;
#pragma unroll
        for (int r = 0; r < 8; ++r) {
            int e = (bl & 3) * 8 + r;
            int o = lane_r * 32 + (e ^ swz);
            float s = red[o] + red[2048 + o] + red[4096 + o] + red[6144 + o];
            int jglob = jt * 128 + jgr * 8 + r;   // < 8192 always
            drow[jglob + (jglob >= 65 ? 3 : 0)] = s + bias[jglob];
        }
    }
    // tail: unit u = (col 8192+u>>4, b-octet u&15); 16 threads: 8b x 2 k-halves
    {
        int slot = tid >> 4;             // 0..15
        int u = slot * 512 + B;
        if (u < 4128) {
            int c = 8192 + (u >> 4);
            int oct = u & 15;
            int sub = tid & 15;
            int b = oct * 8 + (sub & 7);
            int kh = sub >> 3;
            float at = 0.f;
            int kbase = kh * 256;
#pragma unroll 8
            for (int k = 0; k < 256; ++k) {
                int kg = kbase + k;
                at = fmaf(At[kg * 128 + b], W[(size_t)kg * 8450 + c], at);
            }
            float other = __shfl_xor(at, 8);
            if (sub < 8)
                wab[(size_t)b * WSTRIDE + c + 3] = at + other + bias[c];
        }
    }
}

// Decoder (R9-proven). wab row (shifted): w0[0:64], b0[64], pad[65:68),
// W1[68:4164), b1[4164:4228), W2[4228:8324), b2[8324:8388), w3[8388:8452), b3[8452].
// Grid 256 = (b, g-half); 512 thr = 8 waves, wave owns 8 j. lane = g.
__global__ __launch_bounds__(512) void decoder_kernel(const float* __restrict__ wab,
                                                      const float* __restrict__ logP,
                                                      float* __restrict__ out) {
    __shared__ float hX[64 * 65];      // 16.6 KB, h[j][g]
    __shared__ float hY[64 * 65];
    __shared__ float red[8][68];
    int b  = blockIdx.x >> 1;
    int gh = blockIdx.x & 1;
    int tid = threadIdx.x;
    int lane = tid & 63;
    int jq = (tid >> 6) * 8;           // vector path (no readfirstlane)
    int g = gh * 64 + lane;
    bool act = g < 100;
    const float* __restrict__ row = wab + (size_t)b * WSTRIDE;
    float x0 = act ? logP[b * 100 + g] * (1.0f / 3.0f) : 0.0f;
    float c0 = row[64];
#pragma unroll
    for (int t = 0; t < 8; ++t)
        hX[(jq + t) * 65 + lane] = __sinf(30.0f * fmaf(x0, row[jq + t], c0));
    __syncthreads();
    // layer 1
    {
        float a[8];
#pragma unroll
        for (int t = 0; t < 8; ++t) a[t] = row[4164 + jq + t];
#pragma unroll 4
        for (int i = 0; i < 64; ++i) {
            float hi = hX[i * 65 + lane];
            const float* wr = row + 68 + i * 64 + jq;   // 16B aligned
            float4 w0 = *(const float4*)&wr[0];
            float4 w1 = *(const float4*)&wr[4];
            a[0] = fmaf(hi, w0.x, a[0]);  a[1] = fmaf(hi, w0.y, a[1]);
            a[2] = fmaf(hi, w0.z, a[2]);  a[3] = fmaf(hi, w0.w, a[3]);
            a[4] = fmaf(hi, w1.x, a[4]);  a[5] = fmaf(hi, w1.y, a[5]);
            a[6] = fmaf(hi, w1.z, a[6]);  a[7] = fmaf(hi, w1.w, a[7]);
        }
#pragma unroll
        for (int t = 0; t < 8; ++t) hY[(jq + t) * 65 + lane] = __sinf(a[t]);
    }
    __syncthreads();
    // layer 2
    {
        float a[8];
#pragma unroll
        for (int t = 0; t < 8; ++t) a[t] = row[8324 + jq + t];
#pragma unroll 4
        for (int i = 0; i < 64; ++i) {
            float hi = hY[i * 65 + lane];
            const float* wr = row + 4228 + i * 64 + jq;
            float4 w0 = *(const float4*)&wr[0];
            float4 w1 = *(const float4*)&wr[4];
            a[0] = fmaf(hi, w0.x, a[0]);  a[1] = fmaf(hi, w0.y, a[1]);
            a[2] = fmaf(hi, w0.z, a[2]);  a[3] = fmaf(hi, w0.w, a[3]);
            a[4] = fmaf(hi, w1.x, a[4]);  a[5] = fmaf(hi, w1.y, a[5]);
            a[6] = fmaf(hi, w1.z, a[6]);  a[7] = fmaf(hi, w1.w, a[7]);
        }
#pragma unroll
        for (int t = 0; t < 8; ++t) hX[(jq + t) * 65 + lane] = __sinf(a[t]);
    }
    __syncthreads();
    // layer 3
    float p = 0.f;
#pragma unroll
    for (int t = 0; t < 8; ++t)
        p = fmaf(hX[(jq + t) * 65 + lane], row[8388 + jq + t], p);
    red[tid >> 6][lane] = p;
    __syncthreads();
    if (tid < 64 && act) {
        float s = row[8452];
#pragma unroll
        for (int w = 0; w < 8; ++w) s += red[w][lane];
        out[b * 100 + g] = fmaf(s, 500.0f, 1500.0f);
    }
}

extern "C" void kernel_launch(void* const* d_in, const int* in_sizes, int n_in,
                              void* d_out, int out_size, void* d_ws, size_t ws_size,
                              hipStream_t stream) {
    const float* z    = (const float*)d_in[0];
    const float* logP = (const float*)d_in[1];
    const float* hW0  = (const float*)d_in[2];
    const float* hb0  = (const float*)d_in[3];
    const float* hW1  = (const float*)d_in[4];
    const float* hb1  = (const float*)d_in[5];
    const float* hW2  = (const float*)d_in[6];
    const float* hb2  = (const float*)d_in[7];
    const float* hWo  = (const float*)d_in[8];
    const float* hbo  = (const float*)d_in[9];
    float* out = (float*)d_out;

    float* wab = (float*)d_ws;               // 128*8704 floats (4.46 MB)
    float* h0T = wab + 128 * WSTRIDE;        // 512*128 floats (transposed)
    float* h1T = h0T + 512 * 128;
    float* h2T = h1T + 512 * 128;            // total ~5.25 MB

    h0T_kernel<<<512, 128, 0, stream>>>(z, hW0, hb0, h0T);
    gemmT_kernel<<<256, 512, 0, stream>>>(h0T, hW1, hb1, h1T);
    gemmT_kernel<<<256, 512, 0, stream>>>(h1T, hW2, hb2, h2T);
    wabT_kernel<<<512, 256, 0, stream>>>(h2T, hWo, hbo, wab);
    decoder_kernel<<<256, 512, 0, stream>>>(wab, logP, out);
}

// Round 12
// 78.680 us; speedup vs baseline: 2.4039x; 1.0644x over previous
//
#include <hip/hip_runtime.h>

#define WSTRIDE 8704   // padded row stride for wab (shifted layout, max idx 8452)

__device__ __forceinline__ float lrelu(float x) { return x > 0.0f ? x : 0.01f * x; }

// h0T[j][b] = lrelu(sum_l z[b][l]*W0[l][j] + b0[j]); one block per j, lane = b
__global__ __launch_bounds__(128) void h0T_kernel(const float* __restrict__ z,
                                                  const float* __restrict__ W,
                                                  const float* __restrict__ bias,
                                                  float* __restrict__ h0T) {
    int j = blockIdx.x;          // 0..511
    int b = threadIdx.x;         // 0..127
    float zr[16];
    *(float4*)&zr[0]  = *(const float4*)&z[b * 16 + 0];
    *(float4*)&zr[4]  = *(const float4*)&z[b * 16 + 4];
    *(float4*)&zr[8]  = *(const float4*)&z[b * 16 + 8];
    *(float4*)&zr[12] = *(const float4*)&z[b * 16 + 12];
    float acc = bias[j];
#pragma unroll
    for (int l = 0; l < 16; ++l) acc = fmaf(zr[l], W[l * 512 + j], acc);
    h0T[j * 128 + b] = lrelu(acc);
}

// OT[j][b] = lrelu(sum_k At[k][b]*W[k][j] + bias[j])  — R5-proven config.
// tile 64 j x 4 b, k-split 8 (512 thr); At slice in LDS; grid 256 = 8 jt x 32 bt.
__global__ __launch_bounds__(512) void gemmT_kernel(const float* __restrict__ At,
                                                    const float* __restrict__ W,
                                                    const float* __restrict__ bias,
                                                    float* __restrict__ OT) {
    __shared__ __align__(16) float As[512][4];   // 8 KB
    __shared__ float red[8][64][5];              // 10 KB
    int jt = blockIdx.x & 7;
    int bt = blockIdx.x >> 3;          // 0..31
    int tid = threadIdx.x;
    int lane = tid & 63;
    int wid  = __builtin_amdgcn_readfirstlane(tid >> 6);  // 0..7
    int b0 = bt * 4;
#pragma unroll
    for (int r = 0; r < 2; ++r) {
        int p = r * 512 + tid;
        int k = p >> 1, q = p & 1;
        *(float2*)&As[k][q * 2] = *(const float2*)&At[k * 128 + b0 + q * 2];
    }
    __syncthreads();
    int j = jt * 64 + lane;
    float acc[4] = {};
    int k0 = wid * 64;
#pragma unroll 8
    for (int kk = 0; kk < 64; ++kk) {
        int k = k0 + kk;
        float4 a = *(const float4*)&As[k][0];   // LDS broadcast
        float w = W[k * 512 + j];               // coalesced dword
        acc[0] = fmaf(a.x, w, acc[0]);
        acc[1] = fmaf(a.y, w, acc[1]);
        acc[2] = fmaf(a.z, w, acc[2]);
        acc[3] = fmaf(a.w, w, acc[3]);
    }
#pragma unroll
    for (int i = 0; i < 4; ++i) red[wid][lane][i] = acc[i];
    __syncthreads();
    if (tid < 256) {
        int jj = tid >> 2;
        int bb = tid & 3;
        float s = 0.f;
#pragma unroll
        for (int w = 0; w < 8; ++w) s += red[w][jj][bb];
        int jg = jt * 64 + jj;
        OT[jg * 128 + b0 + bb] = lrelu(s + bias[jg]);
    }
}

// wab[b][dest(j)] = sum_k At[k][b]*hWo[k][j] + hbo[j]; dest(j)=j+(j>=65?3:0)
// Tile 128j x 8b x ks4 (256 thr). Lane = (jg 16 x bg 4): jl=8 (W 4x float2),
// bb=2 (ONE LDS b64 broadcast per k -> LDS pipe ~balanced vs 16 FMA).
// acc=16 regs. LDS 17.4 KB: As[512][8] overlaid by reduce buffer.
// Grid 1088 = 68 jt x 16 bt, XCD-swizzled: the 16 b-tiles of one jt sit in one
// XCD's contiguous chunk -> W slice (256 KB) read once from HBM, served by L2.
// jt=66 clamps to cols 8442..8449 (duplicate stores of equal values, benign);
// jt=67 idles.
__global__ __launch_bounds__(256, 4) void wabT_kernel(const float* __restrict__ At,
                                                      const float* __restrict__ W,
                                                      const float* __restrict__ bias,
                                                      float* __restrict__ wab) {
    __shared__ __align__(16) float smem[4 * 64 * 17];   // 17.4 KB
    float (*As)[8] = (float (*)[8])smem;                // 4096 floats (overlay)
    int tid = threadIdx.x;
    int lane = tid & 63;
    int wid = __builtin_amdgcn_readfirstlane(tid >> 6);  // 0..3
    int wgid = (blockIdx.x & 7) * 136 + (blockIdx.x >> 3);  // XCD-grouped
    int jt = wgid >> 4;                // 0..67
    int bt = wgid & 15;                // 0..15
    if (jt >= 67) return;
    int b0blk = bt * 8;
    // stage At[0:512][b0blk:+8] -> As (4 float4 per thread, coalesced pairs)
#pragma unroll
    for (int r = 0; r < 4; ++r) {
        int p = r * 256 + tid;         // 0..1023
        int k = p >> 1, h = (p & 1) * 4;
        *(float4*)&As[k][h] = *(const float4*)&At[k * 128 + b0blk + h];
    }
    __syncthreads();
    int jg = lane & 15;
    int bg = lane >> 4;                // 0..3
    int j0r = jt * 128 + jg * 8;
    int j0 = j0r <= 8442 ? j0r : 8442; // clamp (even -> aligned float2s, +7 in range)
    int k0 = wid * 128;
    const float* __restrict__ Wp = W + (size_t)k0 * 8450 + j0;
    float acc[2][8];
#pragma unroll
    for (int i = 0; i < 2; ++i)
#pragma unroll
        for (int jj = 0; jj < 8; ++jj) acc[i][jj] = 0.f;
#pragma unroll 4
    for (int kk = 0; kk < 128; ++kk) {
        float2 a = *(const float2*)&As[k0 + kk][bg * 2];   // LDS b64 broadcast
        const float* wr = Wp + (size_t)kk * 8450;
        float2 u0 = *(const float2*)(wr + 0);
        float2 u1 = *(const float2*)(wr + 2);
        float2 u2 = *(const float2*)(wr + 4);
        float2 u3 = *(const float2*)(wr + 6);
        float wv[8] = {u0.x, u0.y, u1.x, u1.y, u2.x, u2.y, u3.x, u3.y};
#pragma unroll
        for (int jj = 0; jj < 8; ++jj) {
            acc[0][jj] = fmaf(a.x, wv[jj], acc[0][jj]);
            acc[1][jj] = fmaf(a.y, wv[jj], acc[1][jj]);
        }
    }
    __syncthreads();                   // As dead; overlay reduce [4][64][17]
#pragma unroll
    for (int bbi = 0; bbi < 2; ++bbi)
#pragma unroll
        for (int jj = 0; jj < 8; ++jj)
            smem[(wid * 64 + lane) * 17 + bbi * 8 + jj] = acc[bbi][jj];
    __syncthreads();
    // final: thread t -> j = t&127 (one column), 4 b's (bs = t>>7 half)
    {
        int j = tid & 127;
        int bs = tid >> 7;             // 0..1
        int jgr = j >> 3;
        int jli = j & 7;
        int jgl = jt * 128 + jgr * 8;
        int jbase = jgl <= 8442 ? jgl : 8442;   // mirror the compute clamp
        int jglob = jbase + jli;
        float bj = bias[jglob];
        int dst = jglob + (jglob >= 65 ? 3 : 0);
#pragma unroll
        for (int q = 0; q < 4; ++q) {
            int bl = bs * 4 + q;       // 0..7
            int lane_r = (bl >> 1) * 16 + jgr;
            int i = (bl & 1) * 8 + jli;
            float s = 0.f;
#pragma unroll
            for (int w = 0; w < 4; ++w) s += smem[(w * 64 + lane_r) * 17 + i];
            wab[(size_t)(b0blk + bl) * WSTRIDE + dst] = s + bj;
        }
    }
}

// Decoder (R9 form: 8 waves/CU). wab row (shifted): w0[0:64], b0[64], pad[65:68),
// W1[68:4164), b1[4164:4228), W2[4228:8324), b2[8324:8388), w3[8388:8452), b3[8452].
// Grid 256 = (b, g-half); 512 thr = 8 waves, wave owns 8 j. lane = g.
__global__ __launch_bounds__(512) void decoder_kernel(const float* __restrict__ wab,
                                                      const float* __restrict__ logP,
                                                      float* __restrict__ out) {
    __shared__ float hX[64 * 65];      // 16.6 KB, h[j][g]
    __shared__ float hY[64 * 65];
    __shared__ float red[8][68];
    int b  = blockIdx.x >> 1;
    int gh = blockIdx.x & 1;
    int tid = threadIdx.x;
    int lane = tid & 63;
    int jq = (tid >> 6) * 8;           // vector path (no readfirstlane)
    int g = gh * 64 + lane;
    bool act = g < 100;
    const float* __restrict__ row = wab + (size_t)b * WSTRIDE;
    float x0 = act ? logP[b * 100 + g] * (1.0f / 3.0f) : 0.0f;
    float c0 = row[64];
#pragma unroll
    for (int t = 0; t < 8; ++t)
        hX[(jq + t) * 65 + lane] = __sinf(30.0f * fmaf(x0, row[jq + t], c0));
    __syncthreads();
    // layer 1
    {
        float a[8];
#pragma unroll
        for (int t = 0; t < 8; ++t) a[t] = row[4164 + jq + t];
#pragma unroll 4
        for (int i = 0; i < 64; ++i) {
            float hi = hX[i * 65 + lane];
            const float* wr = row + 68 + i * 64 + jq;   // 16B aligned
            float4 w0 = *(const float4*)&wr[0];
            float4 w1 = *(const float4*)&wr[4];
            a[0] = fmaf(hi, w0.x, a[0]);  a[1] = fmaf(hi, w0.y, a[1]);
            a[2] = fmaf(hi, w0.z, a[2]);  a[3] = fmaf(hi, w0.w, a[3]);
            a[4] = fmaf(hi, w1.x, a[4]);  a[5] = fmaf(hi, w1.y, a[5]);
            a[6] = fmaf(hi, w1.z, a[6]);  a[7] = fmaf(hi, w1.w, a[7]);
        }
#pragma unroll
        for (int t = 0; t < 8; ++t) hY[(jq + t) * 65 + lane] = __sinf(a[t]);
    }
    __syncthreads();
    // layer 2
    {
        float a[8];
#pragma unroll
        for (int t = 0; t < 8; ++t) a[t] = row[8324 + jq + t];
#pragma unroll 4
        for (int i = 0; i < 64; ++i) {
            float hi = hY[i * 65 + lane];
            const float* wr = row + 4228 + i * 64 + jq;
            float4 w0 = *(const float4*)&wr[0];
            float4 w1 = *(const float4*)&wr[4];
            a[0] = fmaf(hi, w0.x, a[0]);  a[1] = fmaf(hi, w0.y, a[1]);
            a[2] = fmaf(hi, w0.z, a[2]);  a[3] = fmaf(hi, w0.w, a[3]);
            a[4] = fmaf(hi, w1.x, a[4]);  a[5] = fmaf(hi, w1.y, a[5]);
            a[6] = fmaf(hi, w1.z, a[6]);  a[7] = fmaf(hi, w1.w, a[7]);
        }
#pragma unroll
        for (int t = 0; t < 8; ++t) hX[(jq + t) * 65 + lane] = __sinf(a[t]);
    }
    __syncthreads();
    // layer 3
    float p = 0.f;
#pragma unroll
    for (int t = 0; t < 8; ++t)
        p = fmaf(hX[(jq + t) * 65 + lane], row[8388 + jq + t], p);
    red[tid >> 6][lane] = p;
    __syncthreads();
    if (tid < 64 && act) {
        float s = row[8452];
#pragma unroll
        for (int w = 0; w < 8; ++w) s += red[w][lane];
        out[b * 100 + g] = fmaf(s, 500.0f, 1500.0f);
    }
}

extern "C" void kernel_launch(void* const* d_in, const int* in_sizes, int n_in,
                              void* d_out, int out_size, void* d_ws, size_t ws_size,
                              hipStream_t stream) {
    const float* z    = (const float*)d_in[0];
    const float* logP = (const float*)d_in[1];
    const float* hW0  = (const float*)d_in[2];
    const float* hb0  = (const float*)d_in[3];
    const float* hW1  = (const float*)d_in[4];
    const float* hb1  = (const float*)d_in[5];
    const float* hW2  = (const float*)d_in[6];
    const float* hb2  = (const float*)d_in[7];
    const float* hWo  = (const float*)d_in[8];
    const float* hbo  = (const float*)d_in[9];
    float* out = (float*)d_out;

    float* wab = (float*)d_ws;               // 128*8704 floats (4.46 MB)
    float* h0T = wab + 128 * WSTRIDE;        // 512*128 floats (transposed)
    float* h1T = h0T + 512 * 128;
    float* h2T = h1T + 512 * 128;            // total ~5.25 MB

    h0T_kernel<<<512, 128, 0, stream>>>(z, hW0, hb0, h0T);
    gemmT_kernel<<<256, 512, 0, stream>>>(h0T, hW1, hb1, h1T);
    gemmT_kernel<<<256, 512, 0, stream>>>(h1T, hW2, hb2, h2T);
    wabT_kernel<<<1088, 256, 0, stream>>>(h2T, hWo, hbo, wab);
    decoder_kernel<<<256, 512, 0, stream>>>(wab, logP, out);
}